// Round 2
// baseline (527.713 us; speedup 1.0000x reference)
//
#include <hip/hip_runtime.h>
#include <math.h>

#define NB 16
#define TLEN 88200
#define W 2048
#define WSTEP 256
#define NF 337            // (88200 - 2048)/256 + 1
#define NMIDI 80

// LDS frame layout: element k lives at 12*(k>>3) + (k&7)  (8 data + 4 pad floats per group)
// -> per-lane window stride 48B => 8 lanes cover all 32 banks, conflict-free b128 reads.

__global__ __launch_bounds__(256) void yin_kernel(const float* __restrict__ x,
                                                  float* __restrict__ out) {
    const int f   = blockIdx.x;   // frame
    const int b   = blockIdx.y;   // batch
    const int tid = threadIdx.x;

    __shared__ float sf[3120];     // padded frame: 260 groups * 12 (groups 256..259 = zero tail)
    __shared__ float cum[2049];    // energy cumsum; reused for cmndfs in phase D/E
    __shared__ float dfa[2048];    // df values
    __shared__ float scanbuf[256];

    const float* xp = x + (size_t)b * TLEN + (size_t)f * WSTEP;

    // ---- Phase A: stage frame (2048 fp32) into padded LDS + zero tail ----
    {
        const float4* xq = (const float4*)xp;           // 16B-aligned (88200*4 and 256*4 are)
        float4 v0 = xq[tid * 2];
        float4 v1 = xq[tid * 2 + 1];
        float* g = &sf[tid * 12];
        *(float4*)(g)     = v0;
        *(float4*)(g + 4) = v1;
        if (tid < 48) sf[3072 + tid] = 0.0f;            // zero groups 256..259
    }
    __syncthreads();

    // ---- Phase B: energy cumsum cum[0..2048] ----
    float loc[8];
    {
        const float* g = &sf[tid * 12];
        float s = 0.0f;
        #pragma unroll
        for (int j = 0; j < 8; j++) { float v = g[j]; s = fmaf(v, v, s); loc[j] = s; }
        scanbuf[tid] = s;
    }
    __syncthreads();
    for (int off = 1; off < 256; off <<= 1) {
        float t = (tid >= off) ? scanbuf[tid - off] : 0.0f;
        __syncthreads();
        scanbuf[tid] += t;
        __syncthreads();
    }
    {
        float excl = (tid > 0) ? scanbuf[tid - 1] : 0.0f;
        #pragma unroll
        for (int j = 0; j < 8; j++) cum[tid * 8 + j + 1] = excl + loc[j];
        if (tid == 0) cum[0] = 0.0f;
    }
    __syncthreads();

    // ---- Phase C: autocorrelation (8 taus/thread, 8x16 register tile) -> df ----
    float acc[8] = {0.f,0.f,0.f,0.f,0.f,0.f,0.f,0.f};
    const int tau0 = tid * 8;
    const int tmax = W - tau0;                          // >= 8
    for (int t = 0; t < tmax; t += 16) {
        const float* A = &sf[(t >> 3) * 12];            // wave-uniform -> LDS broadcast
        const float* B = &sf[((t + tau0) >> 3) * 12];   // 48B/lane stride -> conflict-free
        float4 a0 = *(const float4*)(A);
        float4 a1 = *(const float4*)(A + 4);
        float4 a2 = *(const float4*)(A + 12);
        float4 a3 = *(const float4*)(A + 16);
        float4 b0 = *(const float4*)(B);
        float4 b1 = *(const float4*)(B + 4);
        float4 b2 = *(const float4*)(B + 12);
        float4 b3 = *(const float4*)(B + 16);
        float4 b4 = *(const float4*)(B + 24);
        float4 b5 = *(const float4*)(B + 28);
        float av[16] = {a0.x,a0.y,a0.z,a0.w, a1.x,a1.y,a1.z,a1.w,
                        a2.x,a2.y,a2.z,a2.w, a3.x,a3.y,a3.z,a3.w};
        float bv[24] = {b0.x,b0.y,b0.z,b0.w, b1.x,b1.y,b1.z,b1.w,
                        b2.x,b2.y,b2.z,b2.w, b3.x,b3.y,b3.z,b3.w,
                        b4.x,b4.y,b4.z,b4.w, b5.x,b5.y,b5.z,b5.w};
        #pragma unroll
        for (int i = 0; i < 8; i++) {
            #pragma unroll
            for (int u = 0; u < 16; u++) acc[i] = fmaf(av[u], bv[u + i], acc[i]);
        }
    }
    {
        const float E = cum[W];
        #pragma unroll
        for (int i = 0; i < 8; i++) {
            int tau = tau0 + i;
            dfa[tau] = cum[W - tau] + E - cum[tau] - 2.0f * acc[i];
        }
    }
    __syncthreads();

    // ---- Phase D: cumulative-mean-normalized difference (cmndfs -> cum[]) ----
    float dloc[8];
    {
        float s = 0.0f;
        #pragma unroll
        for (int j = 0; j < 8; j++) {
            int tau = tid * 8 + j;
            float v = (tau == 0) ? 0.0f : dfa[tau];
            s += v; dloc[j] = s;
        }
        scanbuf[tid] = s;
    }
    __syncthreads();
    for (int off = 1; off < 256; off <<= 1) {
        float t = (tid >= off) ? scanbuf[tid - off] : 0.0f;
        __syncthreads();
        scanbuf[tid] += t;
        __syncthreads();
    }
    {
        float excl = (tid > 0) ? scanbuf[tid - 1] : 0.0f;
        #pragma unroll
        for (int j = 0; j < 8; j++) {
            int tau = tid * 8 + j;
            float ds = excl + dloc[j];
            cum[tau] = (tau == 0) ? 1.0f
                                  : dfa[tau] * (float)tau / (ds + 1e-8f);
        }
    }
    __syncthreads();

    // ---- Phase E: sample 80 midi lags with linear interpolation ----
    if (tid < NMIDI) {
        int midi = tid + 5;
        double c = 22050.0 / (440.0 * exp2((double)(midi - 69) / 12.0));
        int fl = (int)c;                        // c in (22, 2021): floor
        float frac = (float)(c - (double)fl);   // ceil-floor == 1 always (c never integer)
        float cf = cum[fl];
        float cc = cum[fl + 1];
        out[(size_t)b * (NMIDI * NF) + (size_t)tid * NF + f] = fmaf(cc - cf, frac, cf);
    }
}

extern "C" void kernel_launch(void* const* d_in, const int* in_sizes, int n_in,
                              void* d_out, int out_size, void* d_ws, size_t ws_size,
                              hipStream_t stream) {
    const float* x = (const float*)d_in[0];
    float* out = (float*)d_out;
    dim3 grid(NF, NB);
    yin_kernel<<<grid, 256, 0, stream>>>(x, out);
}

// Round 3
// 116.927 us; speedup vs baseline: 4.5132x; 4.5132x over previous
//
#include <hip/hip_runtime.h>
#include <math.h>

#define W 2048
#define NB 16
#define TLEN 88200
#define NF 337
#define NMIDI 80

typedef __attribute__((ext_vector_type(8))) short short8;
typedef __attribute__((ext_vector_type(4))) float f32x4;

// XOR swizzle for fp32 arrays: spreads banks, keeps 16B-aligned 4-groups contiguous
__device__ __forceinline__ int swix(int t) { return t ^ (((t >> 5) & 7) << 2); }

// interleaved 8-copy bf16 layout: window of 8 bf16 starting at frame-rel element S
// (S in [-256, 2056], any alignment) lives at ushort offset:
//   s = S&7 (copy), oct = (S+256)>>3, off = oct*64 + ((s+oct)&7)*8   [16B aligned]
__device__ __forceinline__ int xoff(int S) {
    int s = S & 7;
    int oct = (S + 256) >> 3;
    return (oct << 6) + (((s + oct) & 7) << 3);
}

__device__ __forceinline__ unsigned int f2bf(float x) {  // RNE f32->bf16
    unsigned u = __float_as_uint(x);
    u += 0x7FFF + ((u >> 16) & 1);
    return u >> 16;
}

__global__ __launch_bounds__(256) void yin_kernel(const float* __restrict__ x,
                                                  float* __restrict__ out) {
    const int f = blockIdx.x, b = blockIdx.y;
    const int tid = threadIdx.x;
    const int lane = tid & 63, wv = tid >> 6;

    __shared__ unsigned short lds_x[18560];  // 8 shifted bf16 copies, interleaved (37120 B)
    __shared__ float cum[2049];              // swizzled energy cumsum
    __shared__ float dfc[2048];              // swizzled df -> cmndf in place
    __shared__ float wsum[4];

    const float* xp = x + (size_t)b * TLEN + (size_t)f * 256;

    // ---------------- Phase A: stage ----------------
    // thread owns octet o = tid+32 (frame elements [8tid, 8tid+8)), needs 15 values [8tid, 8tid+15)
    float v[16];
    {
        const float4* xq = (const float4*)xp;     // 16B aligned (base mult of 4 floats)
        float4 q0 = xq[2 * tid];
        float4 q1 = xq[2 * tid + 1];
        float4 q2 = xq[2 * tid + 2];
        float4 q3 = xq[2 * tid + 3];
        if (tid == 255) {  // frame zero-pad: elements >= 2048 must be 0 in the copies
            q2 = make_float4(0.f, 0.f, 0.f, 0.f);
            q3 = make_float4(0.f, 0.f, 0.f, 0.f);
        }
        v[0]=q0.x; v[1]=q0.y; v[2]=q0.z; v[3]=q0.w;
        v[4]=q1.x; v[5]=q1.y; v[6]=q1.z; v[7]=q1.w;
        v[8]=q2.x; v[9]=q2.y; v[10]=q2.z; v[11]=q2.w;
        v[12]=q3.x; v[13]=q3.y; v[14]=q3.z; v[15]=q3.w;
    }

    // local energy prefix over own 8 elements
    float pj[8];
    float etot = 0.f;
    #pragma unroll
    for (int j = 0; j < 8; ++j) { etot = fmaf(v[j], v[j], etot); pj[j] = etot; }

    // pack bf16 pairs D[i] = (v[i], v[i+1]); copy s window = v[s..s+8)
    unsigned D[14];
    #pragma unroll
    for (int i = 0; i < 14; ++i) D[i] = f2bf(v[i]) | (f2bf(v[i + 1]) << 16);
    {
        const int oct = tid + 32;
        #pragma unroll
        for (int s = 0; s < 8; ++s) {
            *(uint4*)(lds_x + (oct << 6) + (((s + oct) & 7) << 3)) =
                make_uint4(D[s], D[s + 2], D[s + 4], D[s + 6]);
        }
    }
    // zero pads: octets [0,32) (low) and {288,289} (high), all 8 copies
    {
        int po = tid >> 3, s = tid & 7;            // 256 low-pad writes
        *(uint4*)(lds_x + (po << 6) + (((s + po) & 7) << 3)) = make_uint4(0, 0, 0, 0);
        if (tid < 16) {
            int oct2 = 288 + (tid >> 3), s2 = tid & 7;
            *(uint4*)(lds_x + (oct2 << 6) + (((s2 + oct2) & 7) << 3)) = make_uint4(0, 0, 0, 0);
        }
    }

    // wave-level inclusive scan of per-thread energy totals (shfl, no LDS)
    float inc = etot;
    #pragma unroll
    for (int d = 1; d < 64; d <<= 1) {
        float t = __shfl_up(inc, d, 64);
        if (lane >= d) inc += t;
    }
    if (lane == 63) wsum[wv] = inc;

    __syncthreads();  // B1: lds_x + wsum ready

    // write energy cumsum (fp32, swizzled)
    {
        float base = inc - etot;
        if (wv > 0) base += wsum[0];
        if (wv > 1) base += wsum[1];
        if (wv > 2) base += wsum[2];
        if (tid == 0) cum[0] = 0.0f;  // swix(0)==0
        #pragma unroll
        for (int j = 0; j < 8; ++j) cum[swix(8 * tid + 1 + j)] = base + pj[j];
    }

    // ---------------- Phase C: MFMA autocorrelation ----------------
    // wave wv owns tau-blocks bA=wv (KA=64-8wv chunks) and bB=7-wv (KB=8+8wv chunks)
    // A[m,k] = x~[k - 16m], B_b[k,n] = x~[k + 256b + n]  ->  D[m,n] = acf[256b + 16m + n]
    const int L = lane & 15;
    const int q8 = (lane >> 4) << 3;
    const int bA = wv, bB = 7 - wv;
    const int KA = 64 - 8 * wv, KB = 8 + 8 * wv;

    f32x4 accA = {0.f, 0.f, 0.f, 0.f};
    f32x4 accB = {0.f, 0.f, 0.f, 0.f};

    int oA0 = xoff(q8 - 16 * L);
    int oA1 = xoff(q8 - 16 * L + 32);
    int oP0 = xoff(q8 + L + 256 * bA);
    int oP1 = xoff(q8 + L + 256 * bA + 32);
    int oR0 = xoff(q8 + L + 256 * bB);
    int oR1 = xoff(q8 + L + 256 * bB + 32);

    int kc = 0;
    for (; kc < KB; kc += 2) {                       // both blocks active
        short8 a0 = *(const short8*)(lds_x + oA0);
        short8 p0 = *(const short8*)(lds_x + oP0);
        short8 r0 = *(const short8*)(lds_x + oR0);
        accA = __builtin_amdgcn_mfma_f32_16x16x32_bf16(a0, p0, accA, 0, 0, 0);
        accB = __builtin_amdgcn_mfma_f32_16x16x32_bf16(a0, r0, accB, 0, 0, 0);
        short8 a1 = *(const short8*)(lds_x + oA1);
        short8 p1 = *(const short8*)(lds_x + oP1);
        short8 r1 = *(const short8*)(lds_x + oR1);
        accA = __builtin_amdgcn_mfma_f32_16x16x32_bf16(a1, p1, accA, 0, 0, 0);
        accB = __builtin_amdgcn_mfma_f32_16x16x32_bf16(a1, r1, accB, 0, 0, 0);
        oA0 += 512; oA1 += 512; oP0 += 512; oP1 += 512; oR0 += 512; oR1 += 512;
    }
    for (; kc < KA; kc += 2) {                       // tail: block bA only
        short8 a0 = *(const short8*)(lds_x + oA0);
        short8 p0 = *(const short8*)(lds_x + oP0);
        accA = __builtin_amdgcn_mfma_f32_16x16x32_bf16(a0, p0, accA, 0, 0, 0);
        short8 a1 = *(const short8*)(lds_x + oA1);
        short8 p1 = *(const short8*)(lds_x + oP1);
        accA = __builtin_amdgcn_mfma_f32_16x16x32_bf16(a1, p1, accA, 0, 0, 0);
        oA0 += 512; oA1 += 512; oP0 += 512; oP1 += 512;
    }

    __syncthreads();  // B2: cum complete (written pre-MFMA), accs done

    // ---------------- Phase D: df = cum[W-tau] + E - cum[tau] - 2*acf ----------------
    {
        const float E = cum[swix(2048)];
        const int rq = (lane >> 4) << 6;
        #pragma unroll
        for (int r = 0; r < 4; ++r) {
            int tau = 256 * bA + rq + (r << 4) + L;
            float df = cum[swix(2048 - tau)] + E - cum[swix(tau)] - 2.0f * accA[r];
            dfc[swix(tau)] = df;
        }
        #pragma unroll
        for (int r = 0; r < 4; ++r) {
            int tau = 256 * bB + rq + (r << 4) + L;
            float df = cum[swix(2048 - tau)] + E - cum[swix(tau)] - 2.0f * accB[r];
            dfc[swix(tau)] = df;
        }
    }

    __syncthreads();  // B3: df ready

    // ---------------- Phase E: cmndf (wave 0; lane owns tau in [32l, 32l+32)) ----------------
    if (wv == 0) {
        float dfv[32];
        float s = 0.f;
        #pragma unroll
        for (int u = 0; u < 8; ++u) {
            int el = swix((lane << 5) | (u << 2));
            f32x4 qd = *(const f32x4*)(dfc + el);
            #pragma unroll
            for (int e = 0; e < 4; ++e) {
                float dv = qd[e];
                if (lane == 0 && u == 0 && e == 0) dv = 0.f;  // tau=0 excluded from cumsum
                dfv[u * 4 + e] = dv;
                s += dv;
            }
        }
        float inc2 = s;
        #pragma unroll
        for (int d = 1; d < 64; d <<= 1) {
            float t = __shfl_up(inc2, d, 64);
            if (lane >= d) inc2 += t;
        }
        float run = inc2 - s;  // exclusive offset
        #pragma unroll
        for (int u = 0; u < 8; ++u) {
            f32x4 qo;
            #pragma unroll
            for (int e = 0; e < 4; ++e) {
                int tau = (lane << 5) + (u << 2) + e;
                float dv = dfv[u * 4 + e];
                run += dv;
                float y = (float)tau * dv / (run + 1e-8f);
                if (tau == 0) y = 1.0f;
                qo[e] = y;
            }
            int el = swix((lane << 5) | (u << 2));
            *(f32x4*)(dfc + el) = qo;
        }
    }

    __syncthreads();  // B4: cmndf ready

    // ---------------- Phase F: sample 80 midi lags ----------------
    if (tid < NMIDI) {
        int midi = tid + 5;
        double c = 22050.0 / (440.0 * exp2(((double)(midi - 69)) / 12.0));
        int fl = (int)c;                       // c in (22, 2021), never integer
        float frac = (float)(c - (double)fl);
        float cf = dfc[swix(fl)];
        float cc = dfc[swix(fl + 1)];
        out[(size_t)b * (NMIDI * NF) + (size_t)tid * NF + f] = fmaf(cc - cf, frac, cf);
    }
}

extern "C" void kernel_launch(void* const* d_in, const int* in_sizes, int n_in,
                              void* d_out, int out_size, void* d_ws, size_t ws_size,
                              hipStream_t stream) {
    const float* x = (const float*)d_in[0];
    float* out = (float*)d_out;
    dim3 grid(NF, NB);
    yin_kernel<<<grid, 256, 0, stream>>>(x, out);
}

// Round 4
// 103.464 us; speedup vs baseline: 5.1005x; 1.1301x over previous
//
#include <hip/hip_runtime.h>
#include <math.h>

#define W 2048
#define NB 16
#define TLEN 88200
#define NF 337
#define NMIDI 80

typedef __attribute__((ext_vector_type(8))) short short8;
typedef __attribute__((ext_vector_type(4))) float f32x4;

// XOR swizzle for fp32 arrays: spreads banks, keeps 16B-aligned 4-groups contiguous
__device__ __forceinline__ int swix(int t) { return t ^ (((t >> 5) & 7) << 2); }

// Non-linear quad rotation: bijective in s per octet, and distinct across 8-lane
// groups for BOTH stride-1 octet sequences (staging writes, B-reads) and
// stride-2 octet sequences (A-reads, which a linear (s+oct)&7 left 2-way conflicted).
__device__ __forceinline__ int quadrot(int oct, int s) {
    return (s + 5 * (oct >> 1) + 4 * (oct & 1)) & 7;
}
// window of 8 bf16 starting at frame-rel element S (S in [-256, 2056], any alignment)
__device__ __forceinline__ int xoff(int S) {
    int s = S & 7;
    int oct = (S + 256) >> 3;
    return (oct << 6) + (quadrot(oct, s) << 3);
}

__device__ __forceinline__ unsigned int f2bf(float x) {  // RNE f32->bf16
    unsigned u = __float_as_uint(x);
    u += 0x7FFF + ((u >> 16) & 1);
    return u >> 16;
}

__global__ __launch_bounds__(256) void yin_kernel(const float* __restrict__ x,
                                                  float* __restrict__ out) {
    const int f = blockIdx.x, b = blockIdx.y;
    const int tid = threadIdx.x;
    const int lane = tid & 63, wv = tid >> 6;

    __shared__ unsigned short lds_x[18560];  // 8 shifted bf16 copies, interleaved (37120 B)
    __shared__ float cum[2049];              // swizzled energy cumsum (exclusive at idx)
    __shared__ float dfc[2048];              // swizzled df -> cmndf in place
    __shared__ float wsum[4];
    __shared__ float wdsum[4];

    const float* xp = x + (size_t)b * TLEN + (size_t)f * 256;

    // ---------------- Phase A: stage ----------------
    float v[16];
    {
        const float4* xq = (const float4*)xp;     // 16B aligned
        float4 q0 = xq[2 * tid];
        float4 q1 = xq[2 * tid + 1];
        float4 q2 = xq[2 * tid + 2];
        float4 q3 = xq[2 * tid + 3];
        if (tid == 255) {  // elements >= 2048 must be 0 in the copies
            q2 = make_float4(0.f, 0.f, 0.f, 0.f);
            q3 = make_float4(0.f, 0.f, 0.f, 0.f);
        }
        v[0]=q0.x; v[1]=q0.y; v[2]=q0.z; v[3]=q0.w;
        v[4]=q1.x; v[5]=q1.y; v[6]=q1.z; v[7]=q1.w;
        v[8]=q2.x; v[9]=q2.y; v[10]=q2.z; v[11]=q2.w;
        v[12]=q3.x; v[13]=q3.y; v[14]=q3.z; v[15]=q3.w;
    }

    float pj[8];
    float etot = 0.f;
    #pragma unroll
    for (int j = 0; j < 8; ++j) { etot = fmaf(v[j], v[j], etot); pj[j] = etot; }

    unsigned D[14];
    #pragma unroll
    for (int i = 0; i < 14; ++i) D[i] = f2bf(v[i]) | (f2bf(v[i + 1]) << 16);
    {
        const int oct = tid + 32;
        const int base = oct << 6;
        #pragma unroll
        for (int s = 0; s < 8; ++s) {
            *(uint4*)(lds_x + base + (quadrot(oct, s) << 3)) =
                make_uint4(D[s], D[s + 2], D[s + 4], D[s + 6]);
        }
    }
    {   // zero pads: octets [0,32) and {288,289}, all 8 copies
        int po = tid >> 3, s = tid & 7;
        *(uint4*)(lds_x + (po << 6) + (quadrot(po, s) << 3)) = make_uint4(0, 0, 0, 0);
        if (tid < 16) {
            int oct2 = 288 + (tid >> 3), s2 = tid & 7;
            *(uint4*)(lds_x + (oct2 << 6) + (quadrot(oct2, s2) << 3)) = make_uint4(0, 0, 0, 0);
        }
    }

    // wave inclusive scan of per-thread energy totals
    float inc = etot;
    #pragma unroll
    for (int d = 1; d < 64; d <<= 1) {
        float t = __shfl_up(inc, d, 64);
        if (lane >= d) inc += t;
    }
    if (lane == 63) wsum[wv] = inc;

    __syncthreads();  // B1: lds_x + wsum ready

    // energy cumsum, exclusive layout: cum[t] = sum_{i<t} x^2, aligned f32x4 stores
    {
        float base = inc - etot;
        if (wv > 0) base += wsum[0];
        if (wv > 1) base += wsum[1];
        if (wv > 2) base += wsum[2];
        f32x4 q0 = {base, base + pj[0], base + pj[1], base + pj[2]};
        f32x4 q1 = {base + pj[3], base + pj[4], base + pj[5], base + pj[6]};
        *(f32x4*)(cum + swix(8 * tid)) = q0;
        *(f32x4*)(cum + swix(8 * tid + 4)) = q1;
        if (tid == 255) cum[2048] = base + pj[7];   // swix(2048)==2048
    }

    // ---------------- Phase C: MFMA autocorrelation, paired blocks ----------------
    // wave wv owns blocks bA=2wv (KA=64-16wv chunks), bB=2wv+1 (KB=KA-8 chunks).
    // B_bA(kc) == B_bB(kc-8): single B-stream, accB consumes A-frags from 2 groups ago.
    const int L = lane & 15;
    const int q8 = (lane >> 4) << 3;
    const int bA = 2 * wv;
    const int KA4 = 16 - 4 * wv;   // 4-chunk groups

    const unsigned short* pA[4];
    const unsigned short* pB[4];
    #pragma unroll
    for (int i = 0; i < 4; ++i) {
        pA[i] = lds_x + xoff(q8 - 16 * L + 32 * i);
        pB[i] = lds_x + xoff(q8 + L + 256 * bA + 32 * i);
    }
    // group advance = 16 octets: quad += 5*8 = 40 ≡ 0 (mod 8) -> addr += 1024 exactly

    f32x4 accA = {0.f, 0.f, 0.f, 0.f};
    f32x4 accB = {0.f, 0.f, 0.f, 0.f};
    short8 aM2[4], aM1[4], aC[4], bC[4];

    // g = 0 (accA only)
    #pragma unroll
    for (int i = 0; i < 4; ++i) { aM2[i] = *(const short8*)pA[i]; bC[i] = *(const short8*)pB[i]; }
    #pragma unroll
    for (int i = 0; i < 4; ++i) accA = __builtin_amdgcn_mfma_f32_16x16x32_bf16(aM2[i], bC[i], accA, 0, 0, 0);
    // g = 1 (accA only)
    #pragma unroll
    for (int i = 0; i < 4; ++i) { aM1[i] = *(const short8*)(pA[i] + 1024); bC[i] = *(const short8*)(pB[i] + 1024); }
    #pragma unroll
    for (int i = 0; i < 4; ++i) accA = __builtin_amdgcn_mfma_f32_16x16x32_bf16(aM1[i], bC[i], accA, 0, 0, 0);

    int go = 2048;
    for (int g = 2; g < KA4; ++g) {
        #pragma unroll
        for (int i = 0; i < 4; ++i) { aC[i] = *(const short8*)(pA[i] + go); bC[i] = *(const short8*)(pB[i] + go); }
        #pragma unroll
        for (int i = 0; i < 4; ++i) {
            accA = __builtin_amdgcn_mfma_f32_16x16x32_bf16(aC[i],  bC[i], accA, 0, 0, 0);
            accB = __builtin_amdgcn_mfma_f32_16x16x32_bf16(aM2[i], bC[i], accB, 0, 0, 0);
        }
        #pragma unroll
        for (int i = 0; i < 4; ++i) { aM2[i] = aM1[i]; aM1[i] = aC[i]; }
        go += 1024;
    }

    __syncthreads();  // B2: cum complete, accs done

    // ---------------- Phase D: df = cum[W-tau] + E - cum[tau] - 2*acf ----------------
    {
        const float E = cum[2048];
        const int hi64 = (lane >> 4) << 6;
        #pragma unroll
        for (int r = 0; r < 4; ++r) {
            int tau = (bA << 8) + hi64 + (r << 4) + L;
            dfc[swix(tau)] = cum[swix(2048 - tau)] + E - cum[swix(tau)] - 2.0f * accA[r];
        }
        #pragma unroll
        for (int r = 0; r < 4; ++r) {
            int tau = ((bA + 1) << 8) + hi64 + (r << 4) + L;
            dfc[swix(tau)] = cum[swix(2048 - tau)] + E - cum[swix(tau)] - 2.0f * accB[r];
        }
    }

    __syncthreads();  // B3: df ready

    // ---------------- Phase E: cmndf, all 4 waves (wave wv owns tau in [512wv, 512wv+512)) ----
    float dv[8];
    float excl;
    {
        int t0 = (wv << 9) + (lane << 3);
        f32x4 qa = *(const f32x4*)(dfc + swix(t0));
        f32x4 qb = *(const f32x4*)(dfc + swix(t0 + 4));
        dv[0]=qa.x; dv[1]=qa.y; dv[2]=qa.z; dv[3]=qa.w;
        dv[4]=qb.x; dv[5]=qb.y; dv[6]=qb.z; dv[7]=qb.w;
        if (t0 == 0) dv[0] = 0.f;            // tau=0 excluded from cumsum
        float s = dv[0]+dv[1]+dv[2]+dv[3]+dv[4]+dv[5]+dv[6]+dv[7];
        float inc2 = s;
        #pragma unroll
        for (int d = 1; d < 64; d <<= 1) {
            float tsh = __shfl_up(inc2, d, 64);
            if (lane >= d) inc2 += tsh;
        }
        excl = inc2 - s;
        if (lane == 63) wdsum[wv] = inc2;
    }
    __syncthreads();  // B4: wave sums ready
    {
        int t0 = (wv << 9) + (lane << 3);
        float run = excl;
        if (wv > 0) run += wdsum[0];
        if (wv > 1) run += wdsum[1];
        if (wv > 2) run += wdsum[2];
        f32x4 qo0, qo1;
        #pragma unroll
        for (int j = 0; j < 8; ++j) {
            run += dv[j];
            float y = (float)(t0 + j) * dv[j] / (run + 1e-8f);
            if (t0 + j == 0) y = 1.0f;
            if (j < 4) qo0[j] = y; else qo1[j - 4] = y;
        }
        *(f32x4*)(dfc + swix(t0)) = qo0;
        *(f32x4*)(dfc + swix(t0 + 4)) = qo1;
    }
    __syncthreads();  // B5: cmndf ready

    // ---------------- Phase F: sample 80 midi lags ----------------
    if (tid < NMIDI) {
        float c = 22050.0f / (440.0f * exp2f((float)(tid + 5 - 69) * (1.0f / 12.0f)));
        int fl = (int)c;                      // c in (22, 2021), never near-integer
        float frac = c - (float)fl;
        float cf = dfc[swix(fl)];
        float cc = dfc[swix(fl + 1)];
        out[(size_t)b * (NMIDI * NF) + (size_t)tid * NF + f] = fmaf(cc - cf, frac, cf);
    }
}

extern "C" void kernel_launch(void* const* d_in, const int* in_sizes, int n_in,
                              void* d_out, int out_size, void* d_ws, size_t ws_size,
                              hipStream_t stream) {
    const float* x = (const float*)d_in[0];
    float* out = (float*)d_out;
    dim3 grid(NF, NB);
    yin_kernel<<<grid, 256, 0, stream>>>(x, out);
}